// Round 21
// baseline (121.044 us; speedup 1.0000x reference)
//
#include <hip/hip_runtime.h>
#include <hip/hip_bf16.h>
#include <math.h>

// GCN 2-layer forward on MI355X — v21.
// v20 post-mortem: gemm co-run with scat costs +7us contention (scat's
// latency-critical store chain vs gemm's 51MB stream). v18 showed cnt+gemm
// is the benign pairing. v21: gemm back with cnt (contiguous roles), scat
// unfused; keep WCAP windows / no binScan / fill4+scale.
// Pipeline: cntgemm -> chunkScan -> scat -> fill4(+scale) -> agg1 -> agg2.

constexpr int N   = 100000;
constexpr int E   = 3200000;
constexpr int FIN = 128;
constexpr int FH  = 64;

constexpr int NPB  = 256;                     // nodes per bin
constexpr int NB   = (N + NPB - 1) / NPB;     // 391 bins
constexpr int K    = 6400;                    // edges per chunk
constexpr int NC   = E / K;                   // 500 chunks (exact)
constexpr int NXCD = 8;
constexpr int WCAP = 9216;                    // fixed window cap = 9*1024 (11 sigma)
constexpr int NGB  = 782;                     // gemm blocks (8 waves each)

typedef __attribute__((ext_vector_type(8))) short short8;   // 8 bf16 (4 VGPR)
typedef __attribute__((ext_vector_type(4))) float f32x4;    // MFMA acc
typedef __attribute__((ext_vector_type(2))) float f32x2;

__device__ inline short f2bf(float f) {       // f32 -> bf16 (round-nearest-even)
  unsigned u = __float_as_uint(f);
  return (short)((u + 0x7FFFu + ((u >> 16) & 1u)) >> 16);
}

__device__ inline unsigned char f2fp8(float f) {  // f32 -> fp8 via HW cvt
  return (unsigned char)(__builtin_amdgcn_cvt_pk_fp8_f32(f, f, 0, false) & 0xFF);
}

// Bijective XCD swizzle: each XCD owns a contiguous run of chunks.
__device__ inline int chunk_of(int bid) {
  const int q = NC / NXCD, r = NC % NXCD;     // 62, 4
  int xcd = bid & 7, idx = bid >> 3;
  return (xcd < r) ? xcd * (q + 1) + idx : r * (q + 1) + (xcd - r) * q + idx;
}

// ---- 1: FUSED cnt (bids 0..NC-1) + raw-m1 MFMA gemm (bids NC..) ----
__global__ __launch_bounds__(512) void k_cntgemm(const int* __restrict__ dstA,
                                                 int* __restrict__ segCnt,
                                                 const float* __restrict__ x,
                                                 const float* __restrict__ W1,
                                                 unsigned char* __restrict__ m1) {
  __shared__ int bc[NB];           // cnt role
  __shared__ short8 W1f[16 * 64];  // gemm role, 16 KB
  const int t = threadIdx.x;
  if (blockIdx.x < NC) {
    // ---- cnt role: per-(chunk,bin) counts, bin-major layout ----
    const int w = chunk_of(blockIdx.x);
    const int base = w * K;
    for (int i = t; i < NB; i += 512) bc[i] = 0;
    __syncthreads();
    for (int i = t; i < K; i += 512)
      atomicAdd(&bc[dstA[base + i] >> 8], 1);
    __syncthreads();
    for (int b = t; b < NB; b += 512) segCnt[b * NC + w] = bc[b];
  } else {
    // ---- gemm role: m1_raw = fp8(x @ W1); 8 waves, grid-stride ----
    for (int i = t; i < 16 * 64; i += 512) {
      int frag = i >> 6, l = i & 63;
      int s = frag >> 2, j = frag & 3;
      int kb = 32 * s + 8 * (l >> 4);
      int f  = 16 * j + (l & 15);
      short8 v;
#pragma unroll
      for (int e = 0; e < 8; ++e) v[e] = f2bf(W1[(kb + e) * FH + f]);
      W1f[i] = v;
    }
    __syncthreads();
    const int lane = t & 63;
    const int r16 = lane & 15;   // A row within tile / D col
    const int g4  = lane >> 4;   // k-group
    const int wid = (blockIdx.x - NC) * 8 + (t >> 6);
    for (int T = wid; T < N / 16; T += NGB * 8) {
      const float* xrow = x + (size_t)(16 * T + r16) * FIN + 8 * g4;
      f32x4 acc0 = {0,0,0,0}, acc1 = {0,0,0,0}, acc2 = {0,0,0,0}, acc3 = {0,0,0,0};
#pragma unroll
      for (int s = 0; s < 4; ++s) {
        float4 fa = *(const float4*)(xrow + 32 * s);       // coalesced
        float4 fb = *(const float4*)(xrow + 32 * s + 4);
        short8 a;
        a[0] = f2bf(fa.x); a[1] = f2bf(fa.y); a[2] = f2bf(fa.z); a[3] = f2bf(fa.w);
        a[4] = f2bf(fb.x); a[5] = f2bf(fb.y); a[6] = f2bf(fb.z); a[7] = f2bf(fb.w);
        acc0 = __builtin_amdgcn_mfma_f32_16x16x32_bf16(a, W1f[(s*4+0)*64 + lane], acc0, 0, 0, 0);
        acc1 = __builtin_amdgcn_mfma_f32_16x16x32_bf16(a, W1f[(s*4+1)*64 + lane], acc1, 0, 0, 0);
        acc2 = __builtin_amdgcn_mfma_f32_16x16x32_bf16(a, W1f[(s*4+2)*64 + lane], acc2, 0, 0, 0);
        acc3 = __builtin_amdgcn_mfma_f32_16x16x32_bf16(a, W1f[(s*4+3)*64 + lane], acc3, 0, 0, 0);
      }
      const int nodeBase = 16 * T + 4 * g4;
#pragma unroll
      for (int j = 0; j < 4; ++j) {
        f32x4 acc = (j == 0) ? acc0 : (j == 1) ? acc1 : (j == 2) ? acc2 : acc3;
        size_t fcol = 16 * j + r16;
        m1[(size_t)(nodeBase + 0) * FH + fcol] = f2fp8(acc[0]);  // unscaled
        m1[(size_t)(nodeBase + 1) * FH + fcol] = f2fp8(acc[1]);
        m1[(size_t)(nodeBase + 2) * FH + fcol] = f2fp8(acc[2]);
        m1[(size_t)(nodeBase + 3) * FH + fcol] = f2fp8(acc[3]);
      }
    }
  }
}

// ---- 2: per-bin exclusive scan over chunks -> lp, binTot ----
__global__ __launch_bounds__(512) void k_chunkScan(const int* __restrict__ segCnt,
                                                   int* __restrict__ lp,
                                                   int* __restrict__ binTot) {
  __shared__ int sh[512];
  const int b = blockIdx.x;
  const int t = threadIdx.x;
  int v = (t < NC) ? segCnt[b * NC + t] : 0;
  sh[t] = v;
  __syncthreads();
  for (int off = 1; off < 512; off <<= 1) {
    int tv = (t >= off) ? sh[t - off] : 0;
    __syncthreads();
    sh[t] += tv;
    __syncthreads();
  }
  if (t < NC) lp[b * NC + t] = sh[t] - v;   // exclusive prefix
  if (t == 511) binTot[b] = sh[511];
}

// ---- 3: scatter edges into fixed-capacity bin windows (unfused) ----
__global__ __launch_bounds__(1024) void k_scat(const int* __restrict__ srcA,
                                               const int* __restrict__ dstA,
                                               const int* __restrict__ lp,
                                               unsigned* __restrict__ binned) {
  __shared__ int lpw[NB];
  __shared__ int cur[NB];
  const int w = chunk_of(blockIdx.x);
  const int base = w * K;
  const int t = threadIdx.x;
  for (int b = t; b < NB; b += 1024) {
    lpw[b] = b * WCAP + lp[b * NC + w];
    cur[b] = 0;
  }
  __syncthreads();
  for (int i = t; i < K; i += 1024) {
    int s = srcA[base + i];
    int d = dstA[base + i];
    int b = d >> 8;
    int slot = lpw[b] + atomicAdd(&cur[b], 1);  // adjacent slices same-XCD
    binned[slot] = ((unsigned)(d & 255) << 17) | (unsigned)s;  // src<2^17, dl<2^8
  }
}

// ---- 4: per-bin CSR (single pass, 9 regs = WCAP exactly) + dinv + scale m1 ----
__global__ __launch_bounds__(1024) void k_fill4(const unsigned* __restrict__ binned,
                                                const int* __restrict__ binTot,
                                                int* __restrict__ rowptr,
                                                int* __restrict__ rowEnd,
                                                float* __restrict__ dinv,
                                                int* __restrict__ csr_src,
                                                unsigned char* __restrict__ m1) {
  __shared__ int cnt_s[NPB];
  __shared__ int sh[NPB];
  __shared__ int cur[NPB];
  __shared__ float dv_s[NPB];
  const int b = blockIdx.x;
  const int t = threadIdx.x;
  const int w0 = b * WCAP;
  const int w1 = w0 + binTot[b];
  if (t < NPB) cnt_s[t] = 0;
  __syncthreads();
  unsigned e0_,e1_,e2_,e3_,e4_,e5_,e6_,e7_,e8_;
  unsigned* ebuf[9] = {&e0_,&e1_,&e2_,&e3_,&e4_,&e5_,&e6_,&e7_,&e8_};
#pragma unroll
  for (int r = 0; r < 9; ++r) {              // 9*1024 == WCAP: full coverage
    int i = w0 + t + r * 1024;
    unsigned e = (i < w1) ? binned[i] : 0xFFFFFFFFu;
    *ebuf[r] = e;
    if (e != 0xFFFFFFFFu) atomicAdd(&cnt_s[e >> 17], 1);
  }
  __syncthreads();
  int v = 0;
  if (t < NPB) { v = cnt_s[t]; sh[t] = v; }
  __syncthreads();
  for (int off = 1; off < NPB; off <<= 1) {  // Hillis-Steele inclusive
    int tv = (t < NPB && t >= off) ? sh[t - off] : 0;
    __syncthreads();
    if (t < NPB) sh[t] += tv;
    __syncthreads();
  }
  if (t < NPB) {
    int node = b * NPB + t;
    int start = w0 + sh[t] - v;              // exclusive prefix within window
    float dv = 1.0f / sqrtf((float)(v + 1)); // +1 self-loop
    if (node < N) {
      rowptr[node] = start;
      rowEnd[node] = start + v;
      dinv[node] = dv;
    }
    cur[t] = start;
    dv_s[t] = dv;
  }
  __syncthreads();
#pragma unroll
  for (int r = 0; r < 9; ++r) {
    unsigned e = *ebuf[r];
    if (e != 0xFFFFFFFFu) {
      int p = atomicAdd(&cur[e >> 17], 1);
      csr_src[p] = (int)(e & 0x1FFFFu);      // scatter confined to ~36KB window
    }
  }
  // ---- scale this bin's m1 rows by dinv (raw fp8 -> scaled fp8) ----
  {
    int nl = t >> 2;                         // node-local 0..255
    int q4 = t & 3;                          // uint4 slot (16 fp8) within row
    int node = b * NPB + nl;
    if (node < N) {
      float dv = dv_s[nl];
      uint4* rowp = (uint4*)(m1 + (size_t)node * FH);
      uint4 vv = rowp[q4];
      unsigned dw[4] = {vv.x, vv.y, vv.z, vv.w};
#pragma unroll
      for (int d = 0; d < 4; ++d) {
        f32x2 lo = __builtin_amdgcn_cvt_pk_f32_fp8(dw[d], false);
        f32x2 hi = __builtin_amdgcn_cvt_pk_f32_fp8(dw[d], true);
        unsigned r0 = __builtin_amdgcn_cvt_pk_fp8_f32(lo.x * dv, lo.y * dv, 0, false);
        dw[d] = __builtin_amdgcn_cvt_pk_fp8_f32(hi.x * dv, hi.y * dv, r0, true);
      }
      vv.x = dw[0]; vv.y = dw[1]; vv.z = dw[2]; vv.w = dw[3];
      rowp[q4] = vv;
    }
  }
}

// ---- conv1: 4 nodes/wave, 2 gather streams; fp8 rows (64B = 1 line) ----
__global__ __launch_bounds__(256) void k_agg1(const unsigned char* __restrict__ m1,
                                              const int* __restrict__ rowptr,
                                              const int* __restrict__ rowEnd,
                                              const int* __restrict__ csr_src,
                                              const float* __restrict__ dinv,
                                              const float* __restrict__ b1,
                                              const float* __restrict__ W2,
                                              float* __restrict__ m2) {
  const int lane = threadIdx.x & 63;
  const int half = lane >> 5;
  const int nb   = blockIdx.x * 16 + (threadIdx.x >> 6) * 4;  // exact grid
  const int node0 = nb + half;        // stream 0: nodes nb, nb+1
  const int node1 = nb + 2 + half;    // stream 1: nodes nb+2, nb+3
  const int g2 = (lane >> 3) & 3;
  const int q  = lane & 7;
  const int i  = lane & 31;
  const int s00 = rowptr[node0];
  const int deg0 = rowEnd[node0] - s00;
  const int s01 = rowptr[node1];
  const int deg1 = rowEnd[node1] - s01;
  const uint2* __restrict__ m1q = (const uint2*)m1;  // row = 8 uint2 (64B)
  float x0=0,x1=0,x2=0,x3=0,x4=0,x5=0,x6=0,x7=0;     // stream 0 acc
  float y0=0,y1=0,y2=0,y3=0,y4=0,y5=0,y6=0,y7=0;     // stream 1 acc
  for (int base = 0;; base += 32) {
    int rem0 = deg0 - base, rem1 = deg1 - base;
    if (__all((rem0 <= 0) && (rem1 <= 0))) break;
    int sv0 = (i < rem0) ? csr_src[s00 + base + i] : 0;
    int sv1 = (i < rem1) ? csr_src[s01 + base + i] : 0;
#pragma unroll
    for (int j = 0; j < 32; j += 8) {
      int idx = j + g2;
      int sa = __shfl(sv0, (half << 5) | idx);
      int sb = __shfl(sv1, (half << 5) | idx);
      bool pa = idx < rem0, pb = idx < rem1;
      uint2 va, vb;
      if (pa) va = m1q[(size_t)sa * 8 + q];
      if (pb) vb = m1q[(size_t)sb * 8 + q];
      if (pa) {
        f32x2 f0 = __builtin_amdgcn_cvt_pk_f32_fp8(va.x, false);
        f32x2 f1 = __builtin_amdgcn_cvt_pk_f32_fp8(va.x, true);
        f32x2 f2 = __builtin_amdgcn_cvt_pk_f32_fp8(va.y, false);
        f32x2 f3 = __builtin_amdgcn_cvt_pk_f32_fp8(va.y, true);
        x0 += f0.x; x1 += f0.y; x2 += f1.x; x3 += f1.y;
        x4 += f2.x; x5 += f2.y; x6 += f3.x; x7 += f3.y;
      }
      if (pb) {
        f32x2 f0 = __builtin_amdgcn_cvt_pk_f32_fp8(vb.x, false);
        f32x2 f1 = __builtin_amdgcn_cvt_pk_f32_fp8(vb.x, true);
        f32x2 f2 = __builtin_amdgcn_cvt_pk_f32_fp8(vb.y, false);
        f32x2 f3 = __builtin_amdgcn_cvt_pk_f32_fp8(vb.y, true);
        y0 += f0.x; y1 += f0.y; y2 += f1.x; y3 += f1.y;
        y4 += f2.x; y5 += f2.y; y6 += f3.x; y7 += f3.y;
      }
    }
  }
  // combine 4 edge-subslots within each half, both streams
#pragma unroll
  for (int off = 8; off <= 16; off <<= 1) {
    x0 += __shfl_xor(x0, off); x1 += __shfl_xor(x1, off);
    x2 += __shfl_xor(x2, off); x3 += __shfl_xor(x3, off);
    x4 += __shfl_xor(x4, off); x5 += __shfl_xor(x5, off);
    x6 += __shfl_xor(x6, off); x7 += __shfl_xor(x7, off);
    y0 += __shfl_xor(y0, off); y1 += __shfl_xor(y1, off);
    y2 += __shfl_xor(y2, off); y3 += __shfl_xor(y3, off);
    y4 += __shfl_xor(y4, off); y5 += __shfl_xor(y5, off);
    y6 += __shfl_xor(y6, off); y7 += __shfl_xor(y7, off);
  }
  {  // self-loop rows
    uint2 va = m1q[(size_t)node0 * 8 + q];
    uint2 vb = m1q[(size_t)node1 * 8 + q];
    f32x2 f0 = __builtin_amdgcn_cvt_pk_f32_fp8(va.x, false);
    f32x2 f1 = __builtin_amdgcn_cvt_pk_f32_fp8(va.x, true);
    f32x2 f2 = __builtin_amdgcn_cvt_pk_f32_fp8(va.y, false);
    f32x2 f3 = __builtin_amdgcn_cvt_pk_f32_fp8(va.y, true);
    x0 += f0.x; x1 += f0.y; x2 += f1.x; x3 += f1.y;
    x4 += f2.x; x5 += f2.y; x6 += f3.x; x7 += f3.y;
    f0 = __builtin_amdgcn_cvt_pk_f32_fp8(vb.x, false);
    f1 = __builtin_amdgcn_cvt_pk_f32_fp8(vb.x, true);
    f2 = __builtin_amdgcn_cvt_pk_f32_fp8(vb.y, false);
    f3 = __builtin_amdgcn_cvt_pk_f32_fp8(vb.y, true);
    y0 += f0.x; y1 += f0.y; y2 += f1.x; y3 += f1.y;
    y4 += f2.x; y5 += f2.y; y6 += f3.x; y7 += f3.y;
  }
  const float4 bva = ((const float4*)b1)[q * 2 + 0];   // b1[8q..8q+3]
  const float4 bvb = ((const float4*)b1)[q * 2 + 1];   // b1[8q+4..8q+7]
  const float4 wA = ((const float4*)W2)[q * 4 + 0];    // W2 rows 8q..8q+7
  const float4 wB = ((const float4*)W2)[q * 4 + 1];
  const float4 wC = ((const float4*)W2)[q * 4 + 2];
  const float4 wD = ((const float4*)W2)[q * 4 + 3];
  const float dv0 = dinv[node0];
  const float dv1 = dinv[node1];
  // stream 0 epilogue
  float h0 = fmaxf(fmaf(x0, dv0, bva.x), 0.f);
  float h1 = fmaxf(fmaf(x1, dv0, bva.y), 0.f);
  float h2 = fmaxf(fmaf(x2, dv0, bva.z), 0.f);
  float h3 = fmaxf(fmaf(x3, dv0, bva.w), 0.f);
  float h4 = fmaxf(fmaf(x4, dv0, bvb.x), 0.f);
  float h5 = fmaxf(fmaf(x5, dv0, bvb.y), 0.f);
  float h6 = fmaxf(fmaf(x6, dv0, bvb.z), 0.f);
  float h7 = fmaxf(fmaf(x7, dv0, bvb.w), 0.f);
  float p00 = h0 * wA.x + h1 * wA.z + h2 * wB.x + h3 * wB.z
            + h4 * wC.x + h5 * wC.z + h6 * wD.x + h7 * wD.z;
  float p01 = h0 * wA.y + h1 * wA.w + h2 * wB.y + h3 * wB.w
            + h4 * wC.y + h5 * wC.w + h6 * wD.y + h7 * wD.w;
  // stream 1 epilogue
  h0 = fmaxf(fmaf(y0, dv1, bva.x), 0.f);
  h1 = fmaxf(fmaf(y1, dv1, bva.y), 0.f);
  h2 = fmaxf(fmaf(y2, dv1, bva.z), 0.f);
  h3 = fmaxf(fmaf(y3, dv1, bva.w), 0.f);
  h4 = fmaxf(fmaf(y4, dv1, bvb.x), 0.f);
  h5 = fmaxf(fmaf(y5, dv1, bvb.y), 0.f);
  h6 = fmaxf(fmaf(y6, dv1, bvb.z), 0.f);
  h7 = fmaxf(fmaf(y7, dv1, bvb.w), 0.f);
  float p10 = h0 * wA.x + h1 * wA.z + h2 * wB.x + h3 * wB.z
            + h4 * wC.x + h5 * wC.z + h6 * wD.x + h7 * wD.z;
  float p11 = h0 * wA.y + h1 * wA.w + h2 * wB.y + h3 * wB.w
            + h4 * wC.y + h5 * wC.w + h6 * wD.y + h7 * wD.w;
#pragma unroll
  for (int off = 4; off; off >>= 1) {  // reduce over q (lane bits 0..2)
    p00 += __shfl_xor(p00, off); p01 += __shfl_xor(p01, off);
    p10 += __shfl_xor(p10, off); p11 += __shfl_xor(p11, off);
  }
  if ((lane & 31) == 0) {
    m2[node0 * 2 + 0] = p00 * dv0;
    m2[node0 * 2 + 1] = p01 * dv0;
    m2[node1 * 2 + 0] = p10 * dv1;
    m2[node1 * 2 + 1] = p11 * dv1;
  }
}

// ---- conv2: 2 nodes/wave light gather + bias + generator mask ----
__global__ __launch_bounds__(256) void k_agg2(const float* __restrict__ m2,
                                              const int* __restrict__ rowptr,
                                              const int* __restrict__ rowEnd,
                                              const int* __restrict__ csr_src,
                                              const float* __restrict__ dinv,
                                              const float* __restrict__ b2,
                                              const float* __restrict__ x,
                                              float* __restrict__ out) {
  const int lane = threadIdx.x & 63;
  const int half = lane >> 5;
  const int node = blockIdx.x * 8 + (threadIdx.x >> 6) * 2 + half;  // exact grid
  const int s0 = rowptr[node];
  const int e0 = rowEnd[node];
  float a0 = 0.f, a1 = 0.f;
  for (int e = s0 + (lane & 31); e < e0; e += 32) {
    int s = csr_src[e];
    a0 += m2[s * 2 + 0];
    a1 += m2[s * 2 + 1];
  }
#pragma unroll
  for (int off = 16; off; off >>= 1) {   // reduce within half
    a0 += __shfl_xor(a0, off);
    a1 += __shfl_xor(a1, off);
  }
  if ((lane & 31) == 0) {
    a0 += m2[node * 2 + 0];  // self-loop
    a1 += m2[node * 2 + 1];
    float dv = dinv[node];
    float o0 = a0 * dv + b2[0];
    float o1 = a1 * dv + b2[1];
    float msk = (x[(size_t)node * FIN] == 1.0f) ? 1.0f : 0.0f;
    out[node * 2 + 0] = o0 * msk;
    out[node * 2 + 1] = o1 * msk;
  }
}

extern "C" void kernel_launch(void* const* d_in, const int* in_sizes, int n_in,
                              void* d_out, int out_size, void* d_ws, size_t ws_size,
                              hipStream_t stream) {
  const float* x   = (const float*)d_in[0];
  const int*   ei  = (const int*)d_in[1];  // int32 [2, E] flat
  const float* W1  = (const float*)d_in[2];
  const float* b1  = (const float*)d_in[3];
  const float* W2  = (const float*)d_in[4];
  const float* b2  = (const float*)d_in[5];
  float*       out = (float*)d_out;

  char* w = (char*)d_ws;
  auto alloc = [&](size_t bytes) -> char* {
    char* p = w;
    w += (bytes + 255) & ~(size_t)255;
    return p;
  };
  int*            rowptr  = (int*)alloc((size_t)N * 4);
  int*            rowEnd  = (int*)alloc((size_t)N * 4);
  float*          dinv    = (float*)alloc((size_t)N * 4);
  unsigned*       binned  = (unsigned*)alloc((size_t)NB * WCAP * 4);  // padded
  int*            segCnt  = (int*)alloc((size_t)NB * NC * 4);
  int*            lp      = (int*)alloc((size_t)NB * NC * 4);
  int*            binTot  = (int*)alloc((size_t)NB * 4);
  int*            csr_src = (int*)alloc((size_t)NB * WCAP * 4);       // padded
  unsigned char*  m1      = (unsigned char*)alloc((size_t)N * FH);    // fp8
  float*          m2      = (float*)alloc((size_t)N * 2 * 4);

  const int* srcA = ei;      // edge_index[0]
  const int* dstA = ei + E;  // edge_index[1]

  k_cntgemm<<<dim3(NC + NGB), dim3(512), 0, stream>>>(dstA, segCnt, x, W1, m1);
  k_chunkScan<<<dim3(NB), dim3(512), 0, stream>>>(segCnt, lp, binTot);
  k_scat<<<dim3(NC), dim3(1024), 0, stream>>>(srcA, dstA, lp, binned);
  k_fill4<<<dim3(NB), dim3(1024), 0, stream>>>(binned, binTot, rowptr, rowEnd,
                                               dinv, csr_src, m1);
  k_agg1<<<dim3(N / 16), dim3(256), 0, stream>>>(m1, rowptr, rowEnd, csr_src, dinv, b1, W2, m2);
  k_agg2<<<dim3(N / 8), dim3(256), 0, stream>>>(m2, rowptr, rowEnd, csr_src, dinv, b2, x, out);
}

// Round 22
// 117.934 us; speedup vs baseline: 1.0264x; 1.0264x over previous
//
#include <hip/hip_runtime.h>
#include <hip/hip_bf16.h>
#include <math.h>

// GCN 2-layer forward on MI355X — v22 == v20 (best measured: 118.0us).
// v21 post-mortem: cnt+gemm pairing + unfused scat regressed (+3us) — the
// v20 fused scat||gemm with contiguous role ranges is the empirical optimum.
// Pipeline: cnt -> chunkScan -> scatgemm -> fill4(+scale) -> agg1 -> agg2.

constexpr int N   = 100000;
constexpr int E   = 3200000;
constexpr int FIN = 128;
constexpr int FH  = 64;

constexpr int NPB  = 256;                     // nodes per bin
constexpr int NB   = (N + NPB - 1) / NPB;     // 391 bins
constexpr int K    = 6400;                    // edges per chunk
constexpr int NC   = E / K;                   // 500 chunks (exact)
constexpr int NXCD = 8;
constexpr int WCAP = 9216;                    // fixed window cap = 9*1024 (11 sigma)
constexpr int NGB  = 500;                     // gemm blocks (16 waves each)

typedef __attribute__((ext_vector_type(8))) short short8;   // 8 bf16 (4 VGPR)
typedef __attribute__((ext_vector_type(4))) float f32x4;    // MFMA acc
typedef __attribute__((ext_vector_type(2))) float f32x2;

__device__ inline short f2bf(float f) {       // f32 -> bf16 (round-nearest-even)
  unsigned u = __float_as_uint(f);
  return (short)((u + 0x7FFFu + ((u >> 16) & 1u)) >> 16);
}

__device__ inline unsigned char f2fp8(float f) {  // f32 -> fp8 via HW cvt
  return (unsigned char)(__builtin_amdgcn_cvt_pk_fp8_f32(f, f, 0, false) & 0xFF);
}

// Bijective XCD swizzle: each XCD owns a contiguous run of chunks.
__device__ inline int chunk_of(int bid) {
  const int q = NC / NXCD, r = NC % NXCD;     // 62, 4
  int xcd = bid & 7, idx = bid >> 3;
  return (xcd < r) ? xcd * (q + 1) + idx : r * (q + 1) + (xcd - r) * q + idx;
}

// ---- 1: per-(chunk,bin) counts, bin-major layout ----
__global__ __launch_bounds__(512) void k_cnt(const int* __restrict__ dstA,
                                             int* __restrict__ segCnt) {
  __shared__ int bc[NB];
  const int w = chunk_of(blockIdx.x);
  const int base = w * K;
  for (int i = threadIdx.x; i < NB; i += 512) bc[i] = 0;
  __syncthreads();
  for (int i = threadIdx.x; i < K; i += 512)
    atomicAdd(&bc[dstA[base + i] >> 8], 1);
  __syncthreads();
  for (int b = threadIdx.x; b < NB; b += 512) segCnt[b * NC + w] = bc[b];
}

// ---- 2: per-bin exclusive scan over chunks -> lp, binTot ----
__global__ __launch_bounds__(512) void k_chunkScan(const int* __restrict__ segCnt,
                                                   int* __restrict__ lp,
                                                   int* __restrict__ binTot) {
  __shared__ int sh[512];
  const int b = blockIdx.x;
  const int t = threadIdx.x;
  int v = (t < NC) ? segCnt[b * NC + t] : 0;
  sh[t] = v;
  __syncthreads();
  for (int off = 1; off < 512; off <<= 1) {
    int tv = (t >= off) ? sh[t - off] : 0;
    __syncthreads();
    sh[t] += tv;
    __syncthreads();
  }
  if (t < NC) lp[b * NC + t] = sh[t] - v;   // exclusive prefix
  if (t == 511) binTot[b] = sh[511];
}

// ---- 3: FUSED scat (bids 0..NC-1) + raw-m1 MFMA gemm (bids NC..) ----
__global__ __launch_bounds__(1024) void k_scatgemm(const int* __restrict__ srcA,
                                                   const int* __restrict__ dstA,
                                                   const int* __restrict__ lp,
                                                   unsigned* __restrict__ binned,
                                                   const float* __restrict__ x,
                                                   const float* __restrict__ W1,
                                                   unsigned char* __restrict__ m1) {
  __shared__ int lpw[NB];
  __shared__ int cur[NB];
  __shared__ short8 W1f[16 * 64];  // 16 KB
  const int t = threadIdx.x;
  if (blockIdx.x < NC) {
    // ---- scat role: all 8 XCDs (bid&7 covers 0..7), fixed b*WCAP windows ----
    const int w = chunk_of(blockIdx.x);
    const int base = w * K;
    for (int b = t; b < NB; b += 1024) {
      lpw[b] = b * WCAP + lp[b * NC + w];
      cur[b] = 0;
    }
    __syncthreads();
    for (int i = t; i < K; i += 1024) {
      int s = srcA[base + i];
      int d = dstA[base + i];
      int b = d >> 8;
      int slot = lpw[b] + atomicAdd(&cur[b], 1);
      binned[slot] = ((unsigned)(d & 255) << 17) | (unsigned)s;  // src<2^17, dl<2^8
    }
  } else {
    // ---- gemm role: m1_raw = fp8(x @ W1); 16 waves, grid-stride ----
    for (int i = t; i < 16 * 64; i += 1024) {
      int frag = i >> 6, l = i & 63;
      int s = frag >> 2, j = frag & 3;
      int kb = 32 * s + 8 * (l >> 4);
      int f  = 16 * j + (l & 15);
      short8 v;
#pragma unroll
      for (int e = 0; e < 8; ++e) v[e] = f2bf(W1[(kb + e) * FH + f]);
      W1f[i] = v;
    }
    __syncthreads();
    const int lane = t & 63;
    const int r16 = lane & 15;   // A row within tile / D col
    const int g4  = lane >> 4;   // k-group
    const int wid = (blockIdx.x - NC) * 16 + (t >> 6);  // NGB blocks x 16 waves
    for (int T = wid; T < N / 16; T += NGB * 16) {
      const float* xrow = x + (size_t)(16 * T + r16) * FIN + 8 * g4;
      f32x4 acc0 = {0,0,0,0}, acc1 = {0,0,0,0}, acc2 = {0,0,0,0}, acc3 = {0,0,0,0};
#pragma unroll
      for (int s = 0; s < 4; ++s) {
        float4 fa = *(const float4*)(xrow + 32 * s);       // coalesced
        float4 fb = *(const float4*)(xrow + 32 * s + 4);
        short8 a;
        a[0] = f2bf(fa.x); a[1] = f2bf(fa.y); a[2] = f2bf(fa.z); a[3] = f2bf(fa.w);
        a[4] = f2bf(fb.x); a[5] = f2bf(fb.y); a[6] = f2bf(fb.z); a[7] = f2bf(fb.w);
        acc0 = __builtin_amdgcn_mfma_f32_16x16x32_bf16(a, W1f[(s*4+0)*64 + lane], acc0, 0, 0, 0);
        acc1 = __builtin_amdgcn_mfma_f32_16x16x32_bf16(a, W1f[(s*4+1)*64 + lane], acc1, 0, 0, 0);
        acc2 = __builtin_amdgcn_mfma_f32_16x16x32_bf16(a, W1f[(s*4+2)*64 + lane], acc2, 0, 0, 0);
        acc3 = __builtin_amdgcn_mfma_f32_16x16x32_bf16(a, W1f[(s*4+3)*64 + lane], acc3, 0, 0, 0);
      }
      const int nodeBase = 16 * T + 4 * g4;
#pragma unroll
      for (int j = 0; j < 4; ++j) {
        f32x4 acc = (j == 0) ? acc0 : (j == 1) ? acc1 : (j == 2) ? acc2 : acc3;
        size_t fcol = 16 * j + r16;
        m1[(size_t)(nodeBase + 0) * FH + fcol] = f2fp8(acc[0]);  // unscaled
        m1[(size_t)(nodeBase + 1) * FH + fcol] = f2fp8(acc[1]);
        m1[(size_t)(nodeBase + 2) * FH + fcol] = f2fp8(acc[2]);
        m1[(size_t)(nodeBase + 3) * FH + fcol] = f2fp8(acc[3]);
      }
    }
  }
}

// ---- 4: per-bin CSR (single pass, 9 regs = WCAP exactly) + dinv + scale m1 ----
__global__ __launch_bounds__(1024) void k_fill4(const unsigned* __restrict__ binned,
                                                const int* __restrict__ binTot,
                                                int* __restrict__ rowptr,
                                                int* __restrict__ rowEnd,
                                                float* __restrict__ dinv,
                                                int* __restrict__ csr_src,
                                                unsigned char* __restrict__ m1) {
  __shared__ int cnt_s[NPB];
  __shared__ int sh[NPB];
  __shared__ int cur[NPB];
  __shared__ float dv_s[NPB];
  const int b = blockIdx.x;
  const int t = threadIdx.x;
  const int w0 = b * WCAP;
  const int w1 = w0 + binTot[b];
  if (t < NPB) cnt_s[t] = 0;
  __syncthreads();
  unsigned e0_,e1_,e2_,e3_,e4_,e5_,e6_,e7_,e8_;
  unsigned* ebuf[9] = {&e0_,&e1_,&e2_,&e3_,&e4_,&e5_,&e6_,&e7_,&e8_};
#pragma unroll
  for (int r = 0; r < 9; ++r) {              // 9*1024 == WCAP: full coverage
    int i = w0 + t + r * 1024;
    unsigned e = (i < w1) ? binned[i] : 0xFFFFFFFFu;
    *ebuf[r] = e;
    if (e != 0xFFFFFFFFu) atomicAdd(&cnt_s[e >> 17], 1);
  }
  __syncthreads();
  int v = 0;
  if (t < NPB) { v = cnt_s[t]; sh[t] = v; }
  __syncthreads();
  for (int off = 1; off < NPB; off <<= 1) {  // Hillis-Steele inclusive
    int tv = (t < NPB && t >= off) ? sh[t - off] : 0;
    __syncthreads();
    if (t < NPB) sh[t] += tv;
    __syncthreads();
  }
  if (t < NPB) {
    int node = b * NPB + t;
    int start = w0 + sh[t] - v;              // exclusive prefix within window
    float dv = 1.0f / sqrtf((float)(v + 1)); // +1 self-loop
    if (node < N) {
      rowptr[node] = start;
      rowEnd[node] = start + v;
      dinv[node] = dv;
    }
    cur[t] = start;
    dv_s[t] = dv;
  }
  __syncthreads();
#pragma unroll
  for (int r = 0; r < 9; ++r) {
    unsigned e = *ebuf[r];
    if (e != 0xFFFFFFFFu) {
      int p = atomicAdd(&cur[e >> 17], 1);
      csr_src[p] = (int)(e & 0x1FFFFu);      // scatter confined to ~36KB window
    }
  }
  // ---- scale this bin's m1 rows by dinv (raw fp8 -> scaled fp8) ----
  {
    int nl = t >> 2;                         // node-local 0..255
    int q4 = t & 3;                          // uint4 slot (16 fp8) within row
    int node = b * NPB + nl;
    if (node < N) {
      float dv = dv_s[nl];
      uint4* rowp = (uint4*)(m1 + (size_t)node * FH);
      uint4 vv = rowp[q4];
      unsigned dw[4] = {vv.x, vv.y, vv.z, vv.w};
#pragma unroll
      for (int d = 0; d < 4; ++d) {
        f32x2 lo = __builtin_amdgcn_cvt_pk_f32_fp8(dw[d], false);
        f32x2 hi = __builtin_amdgcn_cvt_pk_f32_fp8(dw[d], true);
        unsigned r0 = __builtin_amdgcn_cvt_pk_fp8_f32(lo.x * dv, lo.y * dv, 0, false);
        dw[d] = __builtin_amdgcn_cvt_pk_fp8_f32(hi.x * dv, hi.y * dv, r0, true);
      }
      vv.x = dw[0]; vv.y = dw[1]; vv.z = dw[2]; vv.w = dw[3];
      rowp[q4] = vv;
    }
  }
}

// ---- conv1: 4 nodes/wave, 2 gather streams; fp8 rows (64B = 1 line) ----
__global__ __launch_bounds__(256) void k_agg1(const unsigned char* __restrict__ m1,
                                              const int* __restrict__ rowptr,
                                              const int* __restrict__ rowEnd,
                                              const int* __restrict__ csr_src,
                                              const float* __restrict__ dinv,
                                              const float* __restrict__ b1,
                                              const float* __restrict__ W2,
                                              float* __restrict__ m2) {
  const int lane = threadIdx.x & 63;
  const int half = lane >> 5;
  const int nb   = blockIdx.x * 16 + (threadIdx.x >> 6) * 4;  // exact grid
  const int node0 = nb + half;        // stream 0: nodes nb, nb+1
  const int node1 = nb + 2 + half;    // stream 1: nodes nb+2, nb+3
  const int g2 = (lane >> 3) & 3;
  const int q  = lane & 7;
  const int i  = lane & 31;
  const int s00 = rowptr[node0];
  const int deg0 = rowEnd[node0] - s00;
  const int s01 = rowptr[node1];
  const int deg1 = rowEnd[node1] - s01;
  const uint2* __restrict__ m1q = (const uint2*)m1;  // row = 8 uint2 (64B)
  float x0=0,x1=0,x2=0,x3=0,x4=0,x5=0,x6=0,x7=0;     // stream 0 acc
  float y0=0,y1=0,y2=0,y3=0,y4=0,y5=0,y6=0,y7=0;     // stream 1 acc
  for (int base = 0;; base += 32) {
    int rem0 = deg0 - base, rem1 = deg1 - base;
    if (__all((rem0 <= 0) && (rem1 <= 0))) break;
    int sv0 = (i < rem0) ? csr_src[s00 + base + i] : 0;
    int sv1 = (i < rem1) ? csr_src[s01 + base + i] : 0;
#pragma unroll
    for (int j = 0; j < 32; j += 8) {
      int idx = j + g2;
      int sa = __shfl(sv0, (half << 5) | idx);
      int sb = __shfl(sv1, (half << 5) | idx);
      bool pa = idx < rem0, pb = idx < rem1;
      uint2 va, vb;
      if (pa) va = m1q[(size_t)sa * 8 + q];
      if (pb) vb = m1q[(size_t)sb * 8 + q];
      if (pa) {
        f32x2 f0 = __builtin_amdgcn_cvt_pk_f32_fp8(va.x, false);
        f32x2 f1 = __builtin_amdgcn_cvt_pk_f32_fp8(va.x, true);
        f32x2 f2 = __builtin_amdgcn_cvt_pk_f32_fp8(va.y, false);
        f32x2 f3 = __builtin_amdgcn_cvt_pk_f32_fp8(va.y, true);
        x0 += f0.x; x1 += f0.y; x2 += f1.x; x3 += f1.y;
        x4 += f2.x; x5 += f2.y; x6 += f3.x; x7 += f3.y;
      }
      if (pb) {
        f32x2 f0 = __builtin_amdgcn_cvt_pk_f32_fp8(vb.x, false);
        f32x2 f1 = __builtin_amdgcn_cvt_pk_f32_fp8(vb.x, true);
        f32x2 f2 = __builtin_amdgcn_cvt_pk_f32_fp8(vb.y, false);
        f32x2 f3 = __builtin_amdgcn_cvt_pk_f32_fp8(vb.y, true);
        y0 += f0.x; y1 += f0.y; y2 += f1.x; y3 += f1.y;
        y4 += f2.x; y5 += f2.y; y6 += f3.x; y7 += f3.y;
      }
    }
  }
  // combine 4 edge-subslots within each half, both streams
#pragma unroll
  for (int off = 8; off <= 16; off <<= 1) {
    x0 += __shfl_xor(x0, off); x1 += __shfl_xor(x1, off);
    x2 += __shfl_xor(x2, off); x3 += __shfl_xor(x3, off);
    x4 += __shfl_xor(x4, off); x5 += __shfl_xor(x5, off);
    x6 += __shfl_xor(x6, off); x7 += __shfl_xor(x7, off);
    y0 += __shfl_xor(y0, off); y1 += __shfl_xor(y1, off);
    y2 += __shfl_xor(y2, off); y3 += __shfl_xor(y3, off);
    y4 += __shfl_xor(y4, off); y5 += __shfl_xor(y5, off);
    y6 += __shfl_xor(y6, off); y7 += __shfl_xor(y7, off);
  }
  {  // self-loop rows
    uint2 va = m1q[(size_t)node0 * 8 + q];
    uint2 vb = m1q[(size_t)node1 * 8 + q];
    f32x2 f0 = __builtin_amdgcn_cvt_pk_f32_fp8(va.x, false);
    f32x2 f1 = __builtin_amdgcn_cvt_pk_f32_fp8(va.x, true);
    f32x2 f2 = __builtin_amdgcn_cvt_pk_f32_fp8(va.y, false);
    f32x2 f3 = __builtin_amdgcn_cvt_pk_f32_fp8(va.y, true);
    x0 += f0.x; x1 += f0.y; x2 += f1.x; x3 += f1.y;
    x4 += f2.x; x5 += f2.y; x6 += f3.x; x7 += f3.y;
    f0 = __builtin_amdgcn_cvt_pk_f32_fp8(vb.x, false);
    f1 = __builtin_amdgcn_cvt_pk_f32_fp8(vb.x, true);
    f2 = __builtin_amdgcn_cvt_pk_f32_fp8(vb.y, false);
    f3 = __builtin_amdgcn_cvt_pk_f32_fp8(vb.y, true);
    y0 += f0.x; y1 += f0.y; y2 += f1.x; y3 += f1.y;
    y4 += f2.x; y5 += f2.y; y6 += f3.x; y7 += f3.y;
  }
  const float4 bva = ((const float4*)b1)[q * 2 + 0];   // b1[8q..8q+3]
  const float4 bvb = ((const float4*)b1)[q * 2 + 1];   // b1[8q+4..8q+7]
  const float4 wA = ((const float4*)W2)[q * 4 + 0];    // W2 rows 8q..8q+7
  const float4 wB = ((const float4*)W2)[q * 4 + 1];
  const float4 wC = ((const float4*)W2)[q * 4 + 2];
  const float4 wD = ((const float4*)W2)[q * 4 + 3];
  const float dv0 = dinv[node0];
  const float dv1 = dinv[node1];
  // stream 0 epilogue
  float h0 = fmaxf(fmaf(x0, dv0, bva.x), 0.f);
  float h1 = fmaxf(fmaf(x1, dv0, bva.y), 0.f);
  float h2 = fmaxf(fmaf(x2, dv0, bva.z), 0.f);
  float h3 = fmaxf(fmaf(x3, dv0, bva.w), 0.f);
  float h4 = fmaxf(fmaf(x4, dv0, bvb.x), 0.f);
  float h5 = fmaxf(fmaf(x5, dv0, bvb.y), 0.f);
  float h6 = fmaxf(fmaf(x6, dv0, bvb.z), 0.f);
  float h7 = fmaxf(fmaf(x7, dv0, bvb.w), 0.f);
  float p00 = h0 * wA.x + h1 * wA.z + h2 * wB.x + h3 * wB.z
            + h4 * wC.x + h5 * wC.z + h6 * wD.x + h7 * wD.z;
  float p01 = h0 * wA.y + h1 * wA.w + h2 * wB.y + h3 * wB.w
            + h4 * wC.y + h5 * wC.w + h6 * wD.y + h7 * wD.w;
  // stream 1 epilogue
  h0 = fmaxf(fmaf(y0, dv1, bva.x), 0.f);
  h1 = fmaxf(fmaf(y1, dv1, bva.y), 0.f);
  h2 = fmaxf(fmaf(y2, dv1, bva.z), 0.f);
  h3 = fmaxf(fmaf(y3, dv1, bva.w), 0.f);
  h4 = fmaxf(fmaf(y4, dv1, bvb.x), 0.f);
  h5 = fmaxf(fmaf(y5, dv1, bvb.y), 0.f);
  h6 = fmaxf(fmaf(y6, dv1, bvb.z), 0.f);
  h7 = fmaxf(fmaf(y7, dv1, bvb.w), 0.f);
  float p10 = h0 * wA.x + h1 * wA.z + h2 * wB.x + h3 * wB.z
            + h4 * wC.x + h5 * wC.z + h6 * wD.x + h7 * wD.z;
  float p11 = h0 * wA.y + h1 * wA.w + h2 * wB.y + h3 * wB.w
            + h4 * wC.y + h5 * wC.w + h6 * wD.y + h7 * wD.w;
#pragma unroll
  for (int off = 4; off; off >>= 1) {  // reduce over q (lane bits 0..2)
    p00 += __shfl_xor(p00, off); p01 += __shfl_xor(p01, off);
    p10 += __shfl_xor(p10, off); p11 += __shfl_xor(p11, off);
  }
  if ((lane & 31) == 0) {
    m2[node0 * 2 + 0] = p00 * dv0;
    m2[node0 * 2 + 1] = p01 * dv0;
    m2[node1 * 2 + 0] = p10 * dv1;
    m2[node1 * 2 + 1] = p11 * dv1;
  }
}

// ---- conv2: 2 nodes/wave light gather + bias + generator mask ----
__global__ __launch_bounds__(256) void k_agg2(const float* __restrict__ m2,
                                              const int* __restrict__ rowptr,
                                              const int* __restrict__ rowEnd,
                                              const int* __restrict__ csr_src,
                                              const float* __restrict__ dinv,
                                              const float* __restrict__ b2,
                                              const float* __restrict__ x,
                                              float* __restrict__ out) {
  const int lane = threadIdx.x & 63;
  const int half = lane >> 5;
  const int node = blockIdx.x * 8 + (threadIdx.x >> 6) * 2 + half;  // exact grid
  const int s0 = rowptr[node];
  const int e0 = rowEnd[node];
  float a0 = 0.f, a1 = 0.f;
  for (int e = s0 + (lane & 31); e < e0; e += 32) {
    int s = csr_src[e];
    a0 += m2[s * 2 + 0];
    a1 += m2[s * 2 + 1];
  }
#pragma unroll
  for (int off = 16; off; off >>= 1) {   // reduce within half
    a0 += __shfl_xor(a0, off);
    a1 += __shfl_xor(a1, off);
  }
  if ((lane & 31) == 0) {
    a0 += m2[node * 2 + 0];  // self-loop
    a1 += m2[node * 2 + 1];
    float dv = dinv[node];
    float o0 = a0 * dv + b2[0];
    float o1 = a1 * dv + b2[1];
    float msk = (x[(size_t)node * FIN] == 1.0f) ? 1.0f : 0.0f;
    out[node * 2 + 0] = o0 * msk;
    out[node * 2 + 1] = o1 * msk;
  }
}

extern "C" void kernel_launch(void* const* d_in, const int* in_sizes, int n_in,
                              void* d_out, int out_size, void* d_ws, size_t ws_size,
                              hipStream_t stream) {
  const float* x   = (const float*)d_in[0];
  const int*   ei  = (const int*)d_in[1];  // int32 [2, E] flat
  const float* W1  = (const float*)d_in[2];
  const float* b1  = (const float*)d_in[3];
  const float* W2  = (const float*)d_in[4];
  const float* b2  = (const float*)d_in[5];
  float*       out = (float*)d_out;

  char* w = (char*)d_ws;
  auto alloc = [&](size_t bytes) -> char* {
    char* p = w;
    w += (bytes + 255) & ~(size_t)255;
    return p;
  };
  int*            rowptr  = (int*)alloc((size_t)N * 4);
  int*            rowEnd  = (int*)alloc((size_t)N * 4);
  float*          dinv    = (float*)alloc((size_t)N * 4);
  unsigned*       binned  = (unsigned*)alloc((size_t)NB * WCAP * 4);  // padded
  int*            segCnt  = (int*)alloc((size_t)NB * NC * 4);
  int*            lp      = (int*)alloc((size_t)NB * NC * 4);
  int*            binTot  = (int*)alloc((size_t)NB * 4);
  int*            csr_src = (int*)alloc((size_t)NB * WCAP * 4);       // padded
  unsigned char*  m1      = (unsigned char*)alloc((size_t)N * FH);    // fp8
  float*          m2      = (float*)alloc((size_t)N * 2 * 4);

  const int* srcA = ei;      // edge_index[0]
  const int* dstA = ei + E;  // edge_index[1]

  k_cnt<<<dim3(NC), dim3(512), 0, stream>>>(dstA, segCnt);
  k_chunkScan<<<dim3(NB), dim3(512), 0, stream>>>(segCnt, lp, binTot);
  k_scatgemm<<<dim3(NC + NGB), dim3(1024), 0, stream>>>(srcA, dstA, lp, binned, x, W1, m1);
  k_fill4<<<dim3(NB), dim3(1024), 0, stream>>>(binned, binTot, rowptr, rowEnd,
                                               dinv, csr_src, m1);
  k_agg1<<<dim3(N / 16), dim3(256), 0, stream>>>(m1, rowptr, rowEnd, csr_src, dinv, b1, W2, m2);
  k_agg2<<<dim3(N / 8), dim3(256), 0, stream>>>(m2, rowptr, rowEnd, csr_src, dinv, b2, x, out);
}